// Round 2
// baseline (1218.795 us; speedup 1.0000x reference)
//
#include <hip/hip_runtime.h>

#define EPS 1e-8f

constexpr int B = 16, C = 19, H = 512, W = 512;
constexpr int HW = H * W;               // 262144 = 2^18
constexpr int NPIX = B * HW;            // 4194304
constexpr long long NPRED = (long long)B * C * HW;  // 79691776

// ws layout (floats):
//   [0..721]  float2 tab[361]: tab[c*19+t] = (ncm[c][t], log(ncm[c][t]+eps))
//   [768]     loss accumulator

__global__ void ncm_kernel(const float* __restrict__ cm, float* __restrict__ ws) {
    int t = threadIdx.x;
    if (t == 0) ws[768] = 0.0f;  // zero the loss accumulator (ws is poisoned each call)
    if (t < C) {
        float row[C];
        float m = -1e30f;
        #pragma unroll
        for (int j = 0; j < C; ++j) { row[j] = cm[t * C + j]; m = fmaxf(m, row[j]); }
        float s = 0.0f;
        #pragma unroll
        for (int j = 0; j < C; ++j) { row[j] = __expf(row[j] - m); s += row[j]; }
        float inv = 1.0f / s;
        float2* tab = (float2*)ws;
        #pragma unroll
        for (int j = 0; j < C; ++j) {
            float v = row[j] * inv;
            tab[t * C + j] = make_float2(v, __logf(v + EPS));
        }
    }
}

__global__ __launch_bounds__(256) void emloss_main(
        const float* __restrict__ logits,
        const int* __restrict__ targets,
        const float* __restrict__ ws,
        float* __restrict__ pred,
        float* __restrict__ loss_acc) {
    __shared__ float2 s_tab[C * C];
    const float2* tab = (const float2*)ws;
    for (int i = threadIdx.x; i < C * C; i += blockDim.x) s_tab[i] = tab[i];
    __syncthreads();

    int p = blockIdx.x * blockDim.x + threadIdx.x;   // one pixel per thread
    int b = p >> 18;                                 // p / HW
    int r = p & (HW - 1);                            // p % HW
    const float* lp = logits + (size_t)b * C * HW + r;
    float*       op = pred   + (size_t)b * C * HW + r;
    int t = targets[p];

    // single load pass: 19 independent coalesced dword loads (256 B/wave each)
    float xs[C];
    #pragma unroll
    for (int c = 0; c < C; ++c) xs[c] = lp[(size_t)c * HW];

    float m = xs[0];
    #pragma unroll
    for (int c = 1; c < C; ++c) m = fmaxf(m, xs[c]);

    // fused exp + loss numerator/denominator (neither needs s):
    //   denom = sum_c ncm[c][t]*e_c
    //   A     = sum_c ncm[c][t]*e_c*(lpre[c][t] + x_c)
    //   loss_px = A/denom - (m + log s)     [log(p+eps) ~= x - m - log s]
    float s = 0.0f, denom = 0.0f, A = 0.0f;
    #pragma unroll
    for (int c = 0; c < C; ++c) {
        float e = __expf(xs[c] - m);
        s += e;
        float2 nt = s_tab[c * C + t];
        float ne = nt.x * e;
        denom += ne;
        A = fmaf(ne, nt.y + xs[c], A);
        xs[c] = e;                         // overwrite x with e (x already consumed)
    }

    float inv_s = 1.0f / s;
    #pragma unroll
    for (int c = 0; c < C; ++c) op[(size_t)c * HW] = xs[c] * inv_s;

    float lsum = A / denom - (m + __logf(s));

    // wave-64 shuffle reduction, one atomic per wave
    #pragma unroll
    for (int off = 32; off > 0; off >>= 1) lsum += __shfl_down(lsum, off);
    if ((threadIdx.x & 63) == 0) atomicAdd(loss_acc, lsum);
}

__global__ void finalize_kernel(const float* __restrict__ acc, float* __restrict__ out) {
    out[0] = -acc[0] / (float)NPIX;
}

extern "C" void kernel_launch(void* const* d_in, const int* in_sizes, int n_in,
                              void* d_out, int out_size, void* d_ws, size_t ws_size,
                              hipStream_t stream) {
    const float* logits  = (const float*)d_in[0];
    const int*   targets = (const int*)d_in[1];
    const float* cm      = (const float*)d_in[2];
    float* out = (float*)d_out;
    float* ws  = (float*)d_ws;

    hipLaunchKernelGGL(ncm_kernel, dim3(1), dim3(64), 0, stream, cm, ws);

    int block = 256;
    int grid = NPIX / block;          // 16384
    hipLaunchKernelGGL(emloss_main, dim3(grid), dim3(block), 0, stream,
                       logits, targets, ws, out, ws + 768);

    hipLaunchKernelGGL(finalize_kernel, dim3(1), dim3(1), 0, stream,
                       ws + 768, out + NPRED);
}